// Round 1
// baseline (169.928 us; speedup 1.0000x reference)
//
#include <hip/hip_runtime.h>
#include <math.h>

// ---- problem constants ----
#define NTOT   8192          // BS*SEQ
#define OFF_IMU  0
#define OFF_ATOM 19660800
#define OFF_SEG  20160000
#define OFF_FC   20659200
#define OFF_FL   20691968

// ---- ws layout (4-byte elements) ----
#define WS_BRIDGE 0        // 32768 floats  (8192 x 4)
#define WS_TR     32768    // 262144 floats (8192 x 32)
#define WS_SEGID  294912   // 8192 ints
#define WS_ENDS   303104   // 4160 ints
#define WS_STARTS 307264   // 4160 ints
#define WS_NK     311424   // 32 ints

static __device__ __forceinline__ int imin(int a, int b) { return a < b ? a : b; }
static __device__ __forceinline__ int imax(int a, int b) { return a > b ? a : b; }

// ============================================================================
// K1: conv1d(6->32,k=3,VALID) + ReLU + half-mean-pool + bridge sigmoid MLP
// one block per n (8192 blocks x 256 threads)
// thread layout: go=tid>>5 owns 4 output channels, gt=tid&31 owns t-chunks of 4
// ============================================================================
__global__ __launch_bounds__(256) void k1_conv_bridge(
    const float* __restrict__ x, const float* __restrict__ conv_w,
    const float* __restrict__ conv_b, const float* __restrict__ W_b1,
    const float* __restrict__ b_b1, float* __restrict__ bridge)
{
    __shared__ float xs[6 * 404];     // padded row stride 404 (16B aligned)
    __shared__ float cws[576];
    __shared__ float pt[64 * 33];     // +1 pad to kill bank conflicts in reduce
    __shared__ float cnn[64];
    const int n = blockIdx.x;
    const int tid = threadIdx.x;

    const float* xn = x + (size_t)n * 2400;
    for (int i = tid; i < 600; i += 256) {
        float4 v = ((const float4*)xn)[i];
        int ic = i / 100, t4 = (i % 100) * 4;
        *(float4*)&xs[ic * 404 + t4] = v;
    }
    for (int i = tid; i < 576; i += 256) cws[i] = conv_w[i];
    __syncthreads();

    const int go = tid >> 5, gt = tid & 31;
    const int oc0 = go * 4;
    float cw[72];
#pragma unroll
    for (int o = 0; o < 4; ++o)
#pragma unroll
        for (int j = 0; j < 18; ++j) cw[o * 18 + j] = cws[(oc0 + o) * 18 + j];
    float cb[4];
#pragma unroll
    for (int o = 0; o < 4; ++o) cb[o] = conv_b[oc0 + o];

    float acc0[4] = {0.f, 0.f, 0.f, 0.f}, acc1[4] = {0.f, 0.f, 0.f, 0.f};
    for (int c = gt; c < 100; c += 32) {
        const int t0 = c * 4;
        float xv[36];
#pragma unroll
        for (int ic = 0; ic < 6; ++ic) {
            float4 a = *(const float4*)&xs[ic * 404 + t0];
            xv[ic * 6 + 0] = a.x; xv[ic * 6 + 1] = a.y;
            xv[ic * 6 + 2] = a.z; xv[ic * 6 + 3] = a.w;
            xv[ic * 6 + 4] = xs[ic * 404 + t0 + 4];
            xv[ic * 6 + 5] = xs[ic * 404 + t0 + 5];
        }
        float s[16];
#pragma unroll
        for (int o = 0; o < 4; ++o)
#pragma unroll
            for (int dt = 0; dt < 4; ++dt) s[o * 4 + dt] = cb[o];
#pragma unroll
        for (int ic = 0; ic < 6; ++ic)
#pragma unroll
            for (int k = 0; k < 3; ++k) {
#pragma unroll
                for (int o = 0; o < 4; ++o) {
                    const float w = cw[o * 18 + ic * 3 + k];
#pragma unroll
                    for (int dt = 0; dt < 4; ++dt)
                        s[o * 4 + dt] = fmaf(w, xv[ic * 6 + dt + k], s[o * 4 + dt]);
                }
            }
#pragma unroll
        for (int dt = 0; dt < 4; ++dt) {
            const int t = t0 + dt;
            const bool h0 = t < 199;
            const bool ok = t < 398;
#pragma unroll
            for (int o = 0; o < 4; ++o) {
                const float r = fmaxf(s[o * 4 + dt], 0.0f);
                acc0[o] += h0 ? r : 0.0f;              // select, not multiply: garbage-safe
                acc1[o] += (ok && !h0) ? r : 0.0f;
            }
        }
    }
#pragma unroll
    for (int o = 0; o < 4; ++o) {
        pt[((oc0 + o) * 2 + 0) * 33 + gt] = acc0[o];
        pt[((oc0 + o) * 2 + 1) * 33 + gt] = acc1[o];
    }
    __syncthreads();
    if (tid < 64) {
        float ssum = 0.f;
#pragma unroll
        for (int j = 0; j < 32; ++j) ssum += pt[tid * 33 + j];
        cnn[tid] = ssum * (1.0f / 199.0f);
    }
    __syncthreads();
    if (tid < 4) {
        float a = b_b1[tid];
#pragma unroll
        for (int f = 0; f < 64; ++f) a = fmaf(cnn[f], W_b1[f * 4 + tid], a);
        bridge[n * 4 + tid] = 1.0f / (1.0f + __expf(-a));
    }
}

// ============================================================================
// K2: forcast (shifted bridge @ W_fc) + masked floss -> d_out regions
// ============================================================================
__global__ __launch_bounds__(256) void k2_forcast(
    const float* __restrict__ bridge, const float* __restrict__ imu_mask,
    const float* __restrict__ W_fc, const float* __restrict__ b_fc,
    float* __restrict__ out)
{
    const int n = blockIdx.x * 256 + threadIdx.x;
    const int s = n & 255;
    float sh[4], cur[4];
#pragma unroll
    for (int j = 0; j < 4; ++j) {
        sh[j] = (s == 0) ? 0.0f : bridge[(n - 1) * 4 + j];
        cur[j] = bridge[n * 4 + j];
    }
    const float fm = ((s == 0) ? 0.0f : 1.0f) * imu_mask[n];
    float fl = 0.0f;
#pragma unroll
    for (int j = 0; j < 4; ++j) {
        float f = b_fc[j];
#pragma unroll
        for (int i = 0; i < 4; ++i) f = fmaf(sh[i], W_fc[i * 4 + j], f);
        out[OFF_FC + n * 4 + j] = f;
        const float d = (f - cur[j]) * fm;
        fl = fmaf(d, d, fl);
    }
    fl *= 0.25f;
    const bool lm = (s >= 2) && (s < 254);
    fl = (fl > 0.001f && lm) ? fl : 0.0f;
    out[OFF_FL + n] = fl;
}

// ============================================================================
// K3: per-batch segmentation: sel/sel2 window-argmax, point/kept, seg_id scan,
//     kp/ends/starts/n_kept.  one block per b (32 x 256)
// ============================================================================
__global__ __launch_bounds__(256) void k3_seg(
    const float* __restrict__ floss, const int* __restrict__ imu_len,
    int* __restrict__ segid_ws, int* __restrict__ ends_ws,
    int* __restrict__ starts_ws, int* __restrict__ nk_ws)
{
    const int b = blockIdx.x, tid = threadIdx.x;
    __shared__ float fl[256];
    __shared__ float sel[256];
    __shared__ float sp[256];
    __shared__ int pk[256];
    __shared__ int sc[2][256];
    __shared__ int kpl[256];
    fl[tid] = floss[b * 256 + tid];
    sp[tid] = 0.0f;
    __syncthreads();
    if (tid < 64) {                       // sel: windows of 4, keep first-max
        const int base = tid * 4;
        float m = fl[base]; int idx = 0;
#pragma unroll
        for (int i = 1; i < 4; ++i) { float v = fl[base + i]; if (v > m) { m = v; idx = i; } }
#pragma unroll
        for (int i = 0; i < 4; ++i) sel[base + i] = (i == idx) ? m : 0.0f;
    }
    __syncthreads();
    if (tid < 63) {                       // sel2 on sel[2:254), 63 windows of 4
        const int base = 2 + tid * 4;
        float m = sel[base]; int idx = 0;
#pragma unroll
        for (int i = 1; i < 4; ++i) { float v = sel[base + i]; if (v > m) { m = v; idx = i; } }
        sp[base + idx] = (m > 0.0f) ? 1.0f : 0.0f;
    }
    __syncthreads();
    int last = (int)rintf((float)imu_len[b] * (1.0f / 256.0f));  // half-even like jnp.round
    last = imin(imax(last, 2), 256);
    const int point = ((sp[tid] > 0.0f) && (tid < last)) ? 1 : 0;
    pk[tid] = point;
    __syncthreads();
    const int pnext = (tid < 255) ? pk[tid + 1] : 0;
    const int bnd = pnext | ((tid + 1 == last) ? 1 : 0);
    const int kept = (point && !bnd) ? 1 : 0;
    __syncthreads();
    pk[tid] = kept;
    sc[0][tid] = kept;
    __syncthreads();
    int src = 0;                          // Hillis-Steele inclusive scan
    for (int off = 1; off < 256; off <<= 1) {
        const int v = sc[src][tid] + ((tid >= off) ? sc[src][tid - off] : 0);
        sc[src ^ 1][tid] = v;
        __syncthreads();
        src ^= 1;
    }
    const int myid = sc[src][tid];
    segid_ws[b * 256 + tid] = myid;
    const int nk = sc[src][255];
    if (kept) kpl[myid - 1] = tid;
    __syncthreads();
    if (tid < 130) {
        ends_ws[b * 130 + tid] = (tid < nk) ? kpl[tid] : last;
        starts_ws[b * 130 + tid] = (tid == 0) ? 0 : ((tid - 1 < nk) ? kpl[tid - 1] : last);
    }
    if (tid == 0) nk_ws[b] = nk;
}

// ============================================================================
// K4: attention (DM=4, 2 heads, segment mask) + transformer block + tr_out
// grid 128 = (b, s-chunk of 64), 64 threads (one per query s)
// NOTE the scrambled hb indexing: hb[b,s] = bridge[s*32 + b]
// ============================================================================
__global__ __launch_bounds__(64) void k4_attn(
    const float* __restrict__ bridge, const int* __restrict__ segid_ws,
    const int* __restrict__ imu_len,
    const float* __restrict__ Wqkv, const float* __restrict__ Wo,
    const float* __restrict__ ln1_g, const float* __restrict__ ln1_b,
    const float* __restrict__ Wf1, const float* __restrict__ bf1,
    const float* __restrict__ Wf2, const float* __restrict__ bf2,
    const float* __restrict__ ln2_g, const float* __restrict__ ln2_b,
    const float* __restrict__ Wout, const float* __restrict__ bout,
    float* __restrict__ tr_ws)
{
    const int b = blockIdx.x >> 2;
    const int chunk = blockIdx.x & 3;
    const int tid = threadIdx.x;
    __shared__ float kv[256][8];
    __shared__ int sid[256];
    for (int s2 = tid; s2 < 256; s2 += 64) {
        const float* hp = bridge + (s2 * 32 + b) * 4;
        const float h0 = hp[0], h1 = hp[1], h2 = hp[2], h3 = hp[3];
#pragma unroll
        for (int e = 0; e < 4; ++e) {
            kv[s2][e]     = h0 * Wqkv[16 + e] + h1 * Wqkv[20 + e] + h2 * Wqkv[24 + e] + h3 * Wqkv[28 + e];
            kv[s2][4 + e] = h0 * Wqkv[32 + e] + h1 * Wqkv[36 + e] + h2 * Wqkv[40 + e] + h3 * Wqkv[44 + e];
        }
        sid[s2] = segid_ws[b * 256 + s2];
    }
    __syncthreads();
    const int s = chunk * 64 + tid;
    const float* hp = bridge + (s * 32 + b) * 4;
    const float hb0 = hp[0], hb1 = hp[1], hb2 = hp[2], hb3 = hp[3];
    float q[4];
#pragma unroll
    for (int e = 0; e < 4; ++e)
        q[e] = hb0 * Wqkv[e] + hb1 * Wqkv[4 + e] + hb2 * Wqkv[8 + e] + hb3 * Wqkv[12 + e];
    int last = (int)rintf((float)imu_len[b] * (1.0f / 256.0f));
    last = imin(imax(last, 2), 256);
    const bool vs = s < last;
    const int ms = sid[s];
    float m0 = -1e30f, l0 = 0.f, a00 = 0.f, a01 = 0.f;
    float m1 = -1e30f, l1 = 0.f, a10 = 0.f, a11 = 0.f;
    const float isq = 0.70710678118654752f;
    for (int j = 0; j < 256; ++j) {
        const bool allowed = (j == s) || (vs && (j < last) && (sid[j] == ms));
        if (!allowed) continue;
        const float sc0 = (q[0] * kv[j][0] + q[1] * kv[j][1]) * isq;
        const float sc1 = (q[2] * kv[j][2] + q[3] * kv[j][3]) * isq;
        {
            const float mn = fmaxf(m0, sc0);
            const float c = __expf(m0 - mn), e = __expf(sc0 - mn);
            l0 = l0 * c + e; a00 = a00 * c + e * kv[j][4]; a01 = a01 * c + e * kv[j][5]; m0 = mn;
        }
        {
            const float mn = fmaxf(m1, sc1);
            const float c = __expf(m1 - mn), e = __expf(sc1 - mn);
            l1 = l1 * c + e; a10 = a10 * c + e * kv[j][6]; a11 = a11 * c + e * kv[j][7]; m1 = mn;
        }
    }
    float ao[4] = {a00 / l0, a01 / l0, a10 / l1, a11 / l1};
    float x1[4];
#pragma unroll
    for (int jj = 0; jj < 4; ++jj)
        x1[jj] = ao[0] * Wo[jj] + ao[1] * Wo[4 + jj] + ao[2] * Wo[8 + jj] + ao[3] * Wo[12 + jj];
    x1[0] += hb0; x1[1] += hb1; x1[2] += hb2; x1[3] += hb3;
    float mean = 0.25f * (x1[0] + x1[1] + x1[2] + x1[3]);
    float var = 0.f;
#pragma unroll
    for (int i = 0; i < 4; ++i) { float d = x1[i] - mean; var += d * d; }
    var *= 0.25f;
    const float rs1 = rsqrtf(var + 1e-5f);
    float h1v[4];
#pragma unroll
    for (int i = 0; i < 4; ++i) h1v[i] = (x1[i] - mean) * rs1 * ln1_g[i] + ln1_b[i];
    float o2[4] = {bf2[0], bf2[1], bf2[2], bf2[3]};
#pragma unroll
    for (int kk = 0; kk < 16; ++kk) {
        float t = bf1[kk];
#pragma unroll
        for (int i = 0; i < 4; ++i) t = fmaf(h1v[i], Wf1[i * 16 + kk], t);
        t = fmaxf(t, 0.0f);
#pragma unroll
        for (int jj = 0; jj < 4; ++jj) o2[jj] = fmaf(t, Wf2[kk * 4 + jj], o2[jj]);
    }
    float x2[4];
#pragma unroll
    for (int i = 0; i < 4; ++i) x2[i] = h1v[i] + o2[i];
    float mean2 = 0.25f * (x2[0] + x2[1] + x2[2] + x2[3]);
    float var2 = 0.f;
#pragma unroll
    for (int i = 0; i < 4; ++i) { float d = x2[i] - mean2; var2 += d * d; }
    var2 *= 0.25f;
    const float rs2 = rsqrtf(var2 + 1e-5f);
    float h2v[4];
#pragma unroll
    for (int i = 0; i < 4; ++i) h2v[i] = (x2[i] - mean2) * rs2 * ln2_g[i] + ln2_b[i];
    float* tp = tr_ws + ((size_t)(b * 256 + s)) * 32;
#pragma unroll
    for (int mm = 0; mm < 32; ++mm)
        tp[mm] = bout[mm] + h2v[0] * Wout[mm] + h2v[1] * Wout[32 + mm]
               + h2v[2] * Wout[64 + mm] + h2v[3] * Wout[96 + mm];
}

// ============================================================================
// K5: atoms: atom_gen = (emb @ Wa + ba)*valid ; seg_interp gather from x
// grid (130, 32), 128 threads (120 active: d*20+i)
// ============================================================================
__global__ __launch_bounds__(128) void k5_atoms(
    const float* __restrict__ x, const float* __restrict__ tr_ws,
    const int* __restrict__ ends_ws, const int* __restrict__ starts_ws,
    const int* __restrict__ nk_ws,
    const float* __restrict__ Wa, const float* __restrict__ ba,
    float* __restrict__ out)
{
    const int a = blockIdx.x;
    const int b = blockIdx.y;
    const int tid = threadIdx.x;
    __shared__ float emb[32];
    const int e = ends_ws[b * 130 + a];
    const int st = starts_ws[b * 130 + a];
    const int nk = nk_ws[b];
    const float valid = (a <= nk) ? 1.0f : 0.0f;
    const int ec = imin(imax(e - 1, 0), 255);
    if (tid < 32) emb[tid] = tr_ws[((size_t)(b * 256 + ec)) * 32 + tid];
    __syncthreads();
    if (tid < 120) {
        float v = ba[tid];
#pragma unroll
        for (int f = 0; f < 32; ++f) v = fmaf(emb[f], Wa[f * 120 + tid], v);
        out[OFF_ATOM + ((size_t)(b * 130 + a)) * 120 + tid] = v * valid;
        const int d = tid / 20, i = tid % 20;
        const int ilen = (e - st) * 400;
        int idx = st * 400 + (i * ilen) / 20;
        idx = imin(imax(idx, 0), 102399);
        const int si = idx / 400, ti = idx % 400;
        const float px = x[(((size_t)b * 256 + si) * 6 + d) * 400 + ti];
        out[OFF_SEG + ((size_t)(b * 130 + a)) * 120 + tid] = px * valid;
    }
}

// ============================================================================
// K6: imu_gen GEMM: (8192x64 relu'd hidden) @ Wd2(64x2400) + bd2
// grid (512 n-tiles of 16, 10 m-tiles of 256), 256 threads, 4x4 micro-tile
// ============================================================================
__global__ __launch_bounds__(256) void k6_imu(
    const float* __restrict__ bridge, const float* __restrict__ Wd1,
    const float* __restrict__ bd1, const float* __restrict__ Wd2,
    const float* __restrict__ bd2, float* __restrict__ out)
{
    __shared__ float hl[1024];        // [f=64][i_n=16]
    const int n0 = blockIdx.x * 16;
    const int mb = blockIdx.y;
    const int tid = threadIdx.x;
    for (int e = tid; e < 1024; e += 256) {
        const int f = e >> 4, i = e & 15;
        const float* br = bridge + (n0 + i) * 4;
        float v = bd1[f] + br[0] * Wd1[f] + br[1] * Wd1[64 + f]
                + br[2] * Wd1[128 + f] + br[3] * Wd1[192 + f];
        hl[e] = fmaxf(v, 0.0f);
    }
    __syncthreads();
    const int gm = tid & 63, gn = tid >> 6;
    const int m0 = mb * 256 + gm * 4;
    if (m0 >= 2400) return;
    float acc[4][4];
#pragma unroll
    for (int r = 0; r < 4; ++r)
#pragma unroll
        for (int c = 0; c < 4; ++c) acc[r][c] = 0.f;
#pragma unroll 8
    for (int f = 0; f < 64; ++f) {
        const float4 h4 = *(const float4*)&hl[f * 16 + gn * 4];
        const float4 w4 = *(const float4*)&Wd2[(size_t)f * 2400 + m0];
        const float hv[4] = {h4.x, h4.y, h4.z, h4.w};
        const float wv[4] = {w4.x, w4.y, w4.z, w4.w};
#pragma unroll
        for (int r = 0; r < 4; ++r)
#pragma unroll
            for (int c = 0; c < 4; ++c) acc[r][c] = fmaf(hv[r], wv[c], acc[r][c]);
    }
    const float4 bb = *(const float4*)&bd2[m0];
#pragma unroll
    for (int r = 0; r < 4; ++r) {
        float4 o;
        o.x = acc[r][0] + bb.x; o.y = acc[r][1] + bb.y;
        o.z = acc[r][2] + bb.z; o.w = acc[r][3] + bb.w;
        *(float4*)&out[OFF_IMU + (size_t)(n0 + gn * 4 + r) * 2400 + m0] = o;
    }
}

// ============================================================================
extern "C" void kernel_launch(void* const* d_in, const int* in_sizes, int n_in,
                              void* d_out, int out_size, void* d_ws, size_t ws_size,
                              hipStream_t stream)
{
    const float* x        = (const float*)d_in[0];
    const float* imu_mask = (const float*)d_in[1];
    const int*   imu_len  = (const int*)  d_in[2];
    const float* conv_w   = (const float*)d_in[3];
    const float* conv_b   = (const float*)d_in[4];
    const float* W_b1     = (const float*)d_in[5];
    const float* b_b1     = (const float*)d_in[6];
    const float* W_fc     = (const float*)d_in[7];
    const float* b_fc     = (const float*)d_in[8];
    const float* Wqkv     = (const float*)d_in[9];
    const float* Wo       = (const float*)d_in[10];
    const float* ln1_g    = (const float*)d_in[11];
    const float* ln1_b    = (const float*)d_in[12];
    const float* Wf1      = (const float*)d_in[13];
    const float* bf1      = (const float*)d_in[14];
    const float* Wf2      = (const float*)d_in[15];
    const float* bf2      = (const float*)d_in[16];
    const float* ln2_g    = (const float*)d_in[17];
    const float* ln2_b    = (const float*)d_in[18];
    const float* Wout     = (const float*)d_in[19];
    const float* bout     = (const float*)d_in[20];
    const float* Wd1      = (const float*)d_in[21];
    const float* bd1      = (const float*)d_in[22];
    const float* Wd2      = (const float*)d_in[23];
    const float* bd2      = (const float*)d_in[24];
    const float* Wa       = (const float*)d_in[25];
    const float* ba       = (const float*)d_in[26];

    float* out = (float*)d_out;
    float* wsf = (float*)d_ws;
    int*   wsi = (int*)d_ws;

    float* bridge = wsf + WS_BRIDGE;
    float* tr_ws  = wsf + WS_TR;
    int* segid  = wsi + WS_SEGID;
    int* ends   = wsi + WS_ENDS;
    int* starts = wsi + WS_STARTS;
    int* nk     = wsi + WS_NK;

    k1_conv_bridge<<<8192, 256, 0, stream>>>(x, conv_w, conv_b, W_b1, b_b1, bridge);
    k2_forcast<<<32, 256, 0, stream>>>(bridge, imu_mask, W_fc, b_fc, out);
    k3_seg<<<32, 256, 0, stream>>>(out + OFF_FL, imu_len, segid, ends, starts, nk);
    k4_attn<<<128, 64, 0, stream>>>(bridge, segid, imu_len, Wqkv, Wo, ln1_g, ln1_b,
                                    Wf1, bf1, Wf2, bf2, ln2_g, ln2_b, Wout, bout, tr_ws);
    k5_atoms<<<dim3(130, 32), 128, 0, stream>>>(x, tr_ws, ends, starts, nk, Wa, ba, out);
    k6_imu<<<dim3(512, 10), 256, 0, stream>>>(bridge, Wd1, bd1, Wd2, bd2, out);
}

// Round 3
// 136.088 us; speedup vs baseline: 1.2487x; 1.2487x over previous
//
#include <hip/hip_runtime.h>
#include <math.h>

// ---- output layout ----
#define OFF_IMU  0
#define OFF_ATOM 19660800
#define OFF_SEG  20160000
#define OFF_FC   20659200
#define OFF_FL   20691968

// ---- ws layout (4-byte elements) ----
#define WS_BRIDGE 0        // 32768 floats  (8192 x 4)
#define WS_TR     32768    // 262144 floats (8192 x 32)
#define WS_SEGID  294912   // 8192 ints
#define WS_ENDS   303104   // 4160 ints
#define WS_STARTS 307264   // 4160 ints
#define WS_NK     311424   // 32 ints

static __device__ __forceinline__ int imin(int a, int b) { return a < b ? a : b; }
static __device__ __forceinline__ int imax(int a, int b) { return a > b ? a : b; }

// ============================================================================
// K1: conv1d(6->32,k=3,VALID) + ReLU + half-mean-pool + bridge sigmoid MLP
// 4096 blocks x 256 threads; 2 samples per block.
// ============================================================================
__global__ __launch_bounds__(256, 2) void k1_conv_bridge(
    const float* __restrict__ x, const float* __restrict__ conv_w,
    const float* __restrict__ conv_b, const float* __restrict__ W_b1,
    const float* __restrict__ b_b1, float* __restrict__ bridge)
{
    __shared__ float xs[2][2424];      // [sample][ic*404 + t]; cols 400..403 zeroed
    __shared__ float pooled[2][64];
    const int tid = threadIdx.x;
    const int n0 = blockIdx.x * 2;

    const float* xn = x + (size_t)n0 * 2400;
    for (int i = tid; i < 1200; i += 256) {
        float4 v = ((const float4*)xn)[i];
        const int smp = i / 600;
        const int r = i - smp * 600;
        const int ic = r / 100, t4 = (r - ic * 100) * 4;
        *(float4*)&xs[smp][ic * 404 + t4] = v;
    }
    if (tid < 48) {                    // zero the pad so mask-FMA is finite-safe
        const int smp = tid / 24, r = tid - smp * 24;
        xs[smp][(r >> 2) * 404 + 400 + (r & 3)] = 0.0f;
    }

    const int g = tid >> 4, l = tid & 15;
    const int smp = g >> 3, og = g & 7, oc0 = og * 4;

    float cw[72];
    {
        const float4* cwp = (const float4*)(conv_w + oc0 * 18);   // 288B-aligned
#pragma unroll
        for (int j = 0; j < 18; ++j) {
            const float4 t = cwp[j];
            cw[j * 4 + 0] = t.x; cw[j * 4 + 1] = t.y;
            cw[j * 4 + 2] = t.z; cw[j * 4 + 3] = t.w;
        }
    }
    float cb[4];
#pragma unroll
    for (int o = 0; o < 4; ++o) cb[o] = conv_b[oc0 + o];

    __syncthreads();

    float acc0[4] = {0.f, 0.f, 0.f, 0.f}, acc1[4] = {0.f, 0.f, 0.f, 0.f};
    const float* xsm = xs[smp];
#pragma unroll
    for (int it = 0; it < 7; ++it) {
        const int c = l + it * 16;
        if (c < 100) {                              // folds away for it<6
            const int t0 = c * 4;
            float s[16];
#pragma unroll
            for (int o = 0; o < 4; ++o)
#pragma unroll
                for (int dt = 0; dt < 4; ++dt) s[o * 4 + dt] = cb[o];
#pragma unroll
            for (int ic = 0; ic < 6; ++ic) {
                const float4 a  = *(const float4*)&xsm[ic * 404 + t0];
                const float4 bq = *(const float4*)&xsm[ic * 404 + t0 + 4];
                const float xv[8] = {a.x, a.y, a.z, a.w, bq.x, bq.y, bq.z, bq.w};
#pragma unroll
                for (int k = 0; k < 3; ++k)
#pragma unroll
                    for (int o = 0; o < 4; ++o) {
                        const float w = cw[o * 18 + ic * 3 + k];
#pragma unroll
                        for (int dt = 0; dt < 4; ++dt)
                            s[o * 4 + dt] = fmaf(w, xv[dt + k], s[o * 4 + dt]);
                    }
            }
#pragma unroll
            for (int dt = 0; dt < 4; ++dt) {
                const int t = t0 + dt;
                const float f0 = (t < 199) ? 1.0f : 0.0f;
                const float f1 = (t >= 199 && t < 398) ? 1.0f : 0.0f;
#pragma unroll
                for (int o = 0; o < 4; ++o) {
                    const float r = fmaxf(s[o * 4 + dt], 0.0f);
                    acc0[o] = fmaf(r, f0, acc0[o]);
                    acc1[o] = fmaf(r, f1, acc1[o]);
                }
            }
        }
    }
    // 16-lane shuffle reduce
#pragma unroll
    for (int off = 1; off < 16; off <<= 1) {
#pragma unroll
        for (int o = 0; o < 4; ++o) {
            acc0[o] += __shfl_xor(acc0[o], off, 16);
            acc1[o] += __shfl_xor(acc1[o], off, 16);
        }
    }
    if (l == 0) {
#pragma unroll
        for (int o = 0; o < 4; ++o) {
            pooled[smp][(oc0 + o) * 2 + 0] = acc0[o];
            pooled[smp][(oc0 + o) * 2 + 1] = acc1[o];
        }
    }
    __syncthreads();
    if (tid < 128) {                   // wave w = sample; lane f = feature
        const int w = tid >> 6, f = tid & 63;
        const float v = pooled[w][f] * (1.0f / 199.0f);
        const float4 wb = *(const float4*)(W_b1 + f * 4);
        float p0 = v * wb.x, p1 = v * wb.y, p2 = v * wb.z, p3 = v * wb.w;
#pragma unroll
        for (int off = 1; off < 64; off <<= 1) {
            p0 += __shfl_xor(p0, off, 64);
            p1 += __shfl_xor(p1, off, 64);
            p2 += __shfl_xor(p2, off, 64);
            p3 += __shfl_xor(p3, off, 64);
        }
        if (f == 0) {
            float* bp = bridge + (size_t)(n0 + w) * 4;
            bp[0] = 1.0f / (1.0f + __expf(-(p0 + b_b1[0])));
            bp[1] = 1.0f / (1.0f + __expf(-(p1 + b_b1[1])));
            bp[2] = 1.0f / (1.0f + __expf(-(p2 + b_b1[2])));
            bp[3] = 1.0f / (1.0f + __expf(-(p3 + b_b1[3])));
        }
    }
}

// ============================================================================
// K23: forcast + masked floss (to d_out) fused with per-batch segmentation.
// one block per b (32 x 256)
// ============================================================================
__global__ __launch_bounds__(256) void k23_forcast_seg(
    const float* __restrict__ bridge, const float* __restrict__ imu_mask,
    const float* __restrict__ W_fc, const float* __restrict__ b_fc,
    const int* __restrict__ imu_len, float* __restrict__ out,
    int* __restrict__ segid_ws, int* __restrict__ ends_ws,
    int* __restrict__ starts_ws, int* __restrict__ nk_ws)
{
    const int b = blockIdx.x, tid = threadIdx.x;
    const int n = b * 256 + tid;
    __shared__ float fl[256];
    __shared__ float sel[256];
    __shared__ float sp[256];
    __shared__ int pk[256];
    __shared__ int sc[2][256];
    __shared__ int kpl[256];

    // ---- forcast + floss ----
    float sh[4], cur[4];
#pragma unroll
    for (int j = 0; j < 4; ++j) {
        sh[j] = (tid == 0) ? 0.0f : bridge[(n - 1) * 4 + j];
        cur[j] = bridge[n * 4 + j];
    }
    const float fm = ((tid == 0) ? 0.0f : 1.0f) * imu_mask[n];
    float flv = 0.0f;
#pragma unroll
    for (int j = 0; j < 4; ++j) {
        float f = b_fc[j];
#pragma unroll
        for (int i = 0; i < 4; ++i) f = fmaf(sh[i], W_fc[i * 4 + j], f);
        out[OFF_FC + n * 4 + j] = f;
        const float d = (f - cur[j]) * fm;
        flv = fmaf(d, d, flv);
    }
    flv *= 0.25f;
    const bool lm = (tid >= 2) && (tid < 254);
    flv = (flv > 0.001f && lm) ? flv : 0.0f;
    out[OFF_FL + n] = flv;

    // ---- segmentation ----
    fl[tid] = flv;
    sp[tid] = 0.0f;
    __syncthreads();
    if (tid < 64) {                       // sel: windows of 4, first-max
        const int base = tid * 4;
        float m = fl[base]; int idx = 0;
#pragma unroll
        for (int i = 1; i < 4; ++i) { float v = fl[base + i]; if (v > m) { m = v; idx = i; } }
#pragma unroll
        for (int i = 0; i < 4; ++i) sel[base + i] = (i == idx) ? m : 0.0f;
    }
    __syncthreads();
    if (tid < 63) {                       // sel2 on sel[2:254), 63 windows of 4
        const int base = 2 + tid * 4;
        float m = sel[base]; int idx = 0;
#pragma unroll
        for (int i = 1; i < 4; ++i) { float v = sel[base + i]; if (v > m) { m = v; idx = i; } }
        sp[base + idx] = (m > 0.0f) ? 1.0f : 0.0f;
    }
    __syncthreads();
    int last = (int)rintf((float)imu_len[b] * (1.0f / 256.0f));  // half-even
    last = imin(imax(last, 2), 256);
    const int point = ((sp[tid] > 0.0f) && (tid < last)) ? 1 : 0;
    pk[tid] = point;
    __syncthreads();
    const int pnext = (tid < 255) ? pk[tid + 1] : 0;
    const int bnd = pnext | ((tid + 1 == last) ? 1 : 0);
    const int kept = (point && !bnd) ? 1 : 0;
    __syncthreads();
    sc[0][tid] = kept;
    __syncthreads();
    int src = 0;                          // Hillis-Steele inclusive scan
    for (int off = 1; off < 256; off <<= 1) {
        const int v = sc[src][tid] + ((tid >= off) ? sc[src][tid - off] : 0);
        sc[src ^ 1][tid] = v;
        __syncthreads();
        src ^= 1;
    }
    const int myid = sc[src][tid];
    segid_ws[b * 256 + tid] = myid;
    const int nk = sc[src][255];
    if (kept) kpl[myid - 1] = tid;
    __syncthreads();
    if (tid < 130) {
        ends_ws[b * 130 + tid] = (tid < nk) ? kpl[tid] : last;
        starts_ws[b * 130 + tid] = (tid == 0) ? 0 : ((tid - 1 < nk) ? kpl[tid - 1] : last);
    }
    if (tid == 0) nk_ws[b] = nk;
}

// ============================================================================
// K4: segment-masked attention (DM=4, 2 heads) + transformer block + tr_out
// grid 256 = (b, 32-query chunk), 256 threads: 8 j-groups x 32 queries,
// LDS online-softmax merge. NOTE hb[b,s] = bridge[s*32 + b] (scrambled).
// exp() is only ever evaluated with argument <= 0 (select, never mask-multiply).
// ============================================================================
__global__ __launch_bounds__(256) void k4_attn(
    const float* __restrict__ bridge, const int* __restrict__ segid_ws,
    const int* __restrict__ imu_len,
    const float* __restrict__ Wqkv, const float* __restrict__ Wo,
    const float* __restrict__ ln1_g, const float* __restrict__ ln1_b,
    const float* __restrict__ Wf1, const float* __restrict__ bf1,
    const float* __restrict__ Wf2, const float* __restrict__ bf2,
    const float* __restrict__ ln2_g, const float* __restrict__ ln2_b,
    const float* __restrict__ Wout, const float* __restrict__ bout,
    float* __restrict__ tr_ws)
{
    const int b = blockIdx.x >> 3;
    const int chunk = blockIdx.x & 7;
    const int tid = threadIdx.x;
    __shared__ float kv[256][8];
    __shared__ int sid[256];
    __shared__ float part[32][8][8];
    {
        const int s2 = tid;
        const float4 h = *(const float4*)(bridge + (size_t)(s2 * 32 + b) * 4);
#pragma unroll
        for (int e = 0; e < 4; ++e) {
            kv[s2][e]     = h.x * Wqkv[16 + e] + h.y * Wqkv[20 + e] + h.z * Wqkv[24 + e] + h.w * Wqkv[28 + e];
            kv[s2][4 + e] = h.x * Wqkv[32 + e] + h.y * Wqkv[36 + e] + h.z * Wqkv[40 + e] + h.w * Wqkv[44 + e];
        }
        sid[s2] = segid_ws[b * 256 + s2];
    }
    __syncthreads();
    int last = (int)rintf((float)imu_len[b] * (1.0f / 256.0f));
    last = imin(imax(last, 2), 256);
    const int lq = tid & 31;
    const int jg = tid >> 5;
    const int sq = chunk * 32 + lq;
    {
        const float4 h = *(const float4*)(bridge + (size_t)(sq * 32 + b) * 4);
        float q[4];
#pragma unroll
        for (int e = 0; e < 4; ++e)
            q[e] = h.x * Wqkv[e] + h.y * Wqkv[4 + e] + h.z * Wqkv[8 + e] + h.w * Wqkv[12 + e];
        const bool vs = sq < last;
        const int ms = sid[sq];
        const float isq = 0.70710678118654752f;
        float m0 = -1e30f, l0 = 0.f, a00 = 0.f, a01 = 0.f;
        float m1 = -1e30f, l1 = 0.f, a10 = 0.f, a11 = 0.f;
#pragma unroll 4
        for (int jj = 0; jj < 32; ++jj) {
            const int j = jg * 32 + jj;
            const bool allowed = (j == sq) || (vs && (j < last) && (sid[j] == ms));
            const float sc0 = (q[0] * kv[j][0] + q[1] * kv[j][1]) * isq;
            const float sc1 = (q[2] * kv[j][2] + q[3] * kv[j][3]) * isq;
            {
                const float mn = allowed ? fmaxf(m0, sc0) : m0;
                const float c = __expf(m0 - mn);                      // arg <= 0 always
                const float e = allowed ? __expf(sc0 - mn) : 0.0f;    // select: no inf*0
                l0 = l0 * c + e; a00 = a00 * c + e * kv[j][4]; a01 = a01 * c + e * kv[j][5]; m0 = mn;
            }
            {
                const float mn = allowed ? fmaxf(m1, sc1) : m1;
                const float c = __expf(m1 - mn);
                const float e = allowed ? __expf(sc1 - mn) : 0.0f;
                l1 = l1 * c + e; a10 = a10 * c + e * kv[j][6]; a11 = a11 * c + e * kv[j][7]; m1 = mn;
            }
        }
        float* pp = part[lq][jg];
        pp[0] = m0; pp[1] = l0; pp[2] = a00; pp[3] = a01;
        pp[4] = m1; pp[5] = l1; pp[6] = a10; pp[7] = a11;
    }
    __syncthreads();
    if (tid < 32) {
        const int s = chunk * 32 + tid;
        float M0 = -1e30f, L0 = 0.f, A00 = 0.f, A01 = 0.f;
        float M1 = -1e30f, L1 = 0.f, A10 = 0.f, A11 = 0.f;
#pragma unroll
        for (int p = 0; p < 8; ++p) {
            const float* pp = part[tid][p];
            {
                const float mn = fmaxf(M0, pp[0]);
                const float c0 = __expf(M0 - mn), c1 = __expf(pp[0] - mn);   // args <= 0
                L0 = L0 * c0 + pp[1] * c1; A00 = A00 * c0 + pp[2] * c1; A01 = A01 * c0 + pp[3] * c1; M0 = mn;
            }
            {
                const float mn = fmaxf(M1, pp[4]);
                const float c0 = __expf(M1 - mn), c1 = __expf(pp[4] - mn);
                L1 = L1 * c0 + pp[5] * c1; A10 = A10 * c0 + pp[6] * c1; A11 = A11 * c0 + pp[7] * c1; M1 = mn;
            }
        }
        const float4 h = *(const float4*)(bridge + (size_t)(s * 32 + b) * 4);
        const float hb0 = h.x, hb1 = h.y, hb2 = h.z, hb3 = h.w;
        float ao[4] = {A00 / L0, A01 / L0, A10 / L1, A11 / L1};
        float x1[4];
#pragma unroll
        for (int jj = 0; jj < 4; ++jj)
            x1[jj] = ao[0] * Wo[jj] + ao[1] * Wo[4 + jj] + ao[2] * Wo[8 + jj] + ao[3] * Wo[12 + jj];
        x1[0] += hb0; x1[1] += hb1; x1[2] += hb2; x1[3] += hb3;
        float mean = 0.25f * (x1[0] + x1[1] + x1[2] + x1[3]);
        float var = 0.f;
#pragma unroll
        for (int i = 0; i < 4; ++i) { float d = x1[i] - mean; var += d * d; }
        var *= 0.25f;
        const float rs1 = rsqrtf(var + 1e-5f);
        float h1v[4];
#pragma unroll
        for (int i = 0; i < 4; ++i) h1v[i] = (x1[i] - mean) * rs1 * ln1_g[i] + ln1_b[i];
        float o2[4] = {bf2[0], bf2[1], bf2[2], bf2[3]};
#pragma unroll
        for (int kk = 0; kk < 16; ++kk) {
            float t = bf1[kk];
#pragma unroll
            for (int i = 0; i < 4; ++i) t = fmaf(h1v[i], Wf1[i * 16 + kk], t);
            t = fmaxf(t, 0.0f);
#pragma unroll
            for (int jj = 0; jj < 4; ++jj) o2[jj] = fmaf(t, Wf2[kk * 4 + jj], o2[jj]);
        }
        float x2[4];
#pragma unroll
        for (int i = 0; i < 4; ++i) x2[i] = h1v[i] + o2[i];
        float mean2 = 0.25f * (x2[0] + x2[1] + x2[2] + x2[3]);
        float var2 = 0.f;
#pragma unroll
        for (int i = 0; i < 4; ++i) { float d = x2[i] - mean2; var2 += d * d; }
        var2 *= 0.25f;
        const float rs2 = rsqrtf(var2 + 1e-5f);
        float h2v[4];
#pragma unroll
        for (int i = 0; i < 4; ++i) h2v[i] = (x2[i] - mean2) * rs2 * ln2_g[i] + ln2_b[i];
        float* tp = tr_ws + ((size_t)(b * 256 + s)) * 32;
#pragma unroll
        for (int mm = 0; mm < 32; ++mm)
            tp[mm] = bout[mm] + h2v[0] * Wout[mm] + h2v[1] * Wout[32 + mm]
                   + h2v[2] * Wout[64 + mm] + h2v[3] * Wout[96 + mm];
    }
}

// ============================================================================
// K5: atoms: atom_gen = (emb @ Wa + ba)*valid ; seg_interp gather from x
// grid (130, 32), 128 threads (120 active: d*20+i)
// ============================================================================
__global__ __launch_bounds__(128) void k5_atoms(
    const float* __restrict__ x, const float* __restrict__ tr_ws,
    const int* __restrict__ ends_ws, const int* __restrict__ starts_ws,
    const int* __restrict__ nk_ws,
    const float* __restrict__ Wa, const float* __restrict__ ba,
    float* __restrict__ out)
{
    const int a = blockIdx.x;
    const int b = blockIdx.y;
    const int tid = threadIdx.x;
    __shared__ float emb[32];
    const int e = ends_ws[b * 130 + a];
    const int st = starts_ws[b * 130 + a];
    const int nk = nk_ws[b];
    const float valid = (a <= nk) ? 1.0f : 0.0f;
    const int ec = imin(imax(e - 1, 0), 255);
    if (tid < 32) emb[tid] = tr_ws[((size_t)(b * 256 + ec)) * 32 + tid];
    __syncthreads();
    if (tid < 120) {
        float v = ba[tid];
#pragma unroll
        for (int f = 0; f < 32; ++f) v = fmaf(emb[f], Wa[f * 120 + tid], v);
        out[OFF_ATOM + ((size_t)(b * 130 + a)) * 120 + tid] = v * valid;
        const int d = tid / 20, i = tid % 20;
        const int ilen = (e - st) * 400;
        int idx = st * 400 + (i * ilen) / 20;
        idx = imin(imax(idx, 0), 102399);
        const int si = idx / 400, ti = idx % 400;
        const float px = x[(((size_t)b * 256 + si) * 6 + d) * 400 + ti];
        out[OFF_SEG + ((size_t)(b * 130 + a)) * 120 + tid] = px * valid;
    }
}

// ============================================================================
// K6: imu_gen GEMM: relu(bridge@Wd1+bd1) @ Wd2(64x2400) + bd2
// grid (256 n-tiles of 32, 10 m-tiles of 256), 256 threads, 8x4 micro-tile
// ============================================================================
__global__ __launch_bounds__(256) void k6_imu(
    const float* __restrict__ bridge, const float* __restrict__ Wd1,
    const float* __restrict__ bd1, const float* __restrict__ Wd2,
    const float* __restrict__ bd2, float* __restrict__ out)
{
    __shared__ float hl[64 * 32];     // [f][i]
    const int n0 = blockIdx.x * 32;
    const int mb = blockIdx.y;
    const int tid = threadIdx.x;
    for (int e = tid; e < 2048; e += 256) {
        const int f = e >> 5, i = e & 31;
        const float4 br = *(const float4*)(bridge + (size_t)(n0 + i) * 4);
        const float v = bd1[f] + br.x * Wd1[f] + br.y * Wd1[64 + f]
                      + br.z * Wd1[128 + f] + br.w * Wd1[192 + f];
        hl[f * 32 + i] = fmaxf(v, 0.0f);
    }
    __syncthreads();
    const int gm = tid & 63, gn = tid >> 6;
    const int m0 = mb * 256 + gm * 4;
    if (m0 >= 2400) return;
    float acc[8][4];
#pragma unroll
    for (int r = 0; r < 8; ++r)
#pragma unroll
        for (int c = 0; c < 4; ++c) acc[r][c] = 0.f;
#pragma unroll 4
    for (int f = 0; f < 64; ++f) {
        const float4 w4 = *(const float4*)&Wd2[(size_t)f * 2400 + m0];
        const float4 h0 = *(const float4*)&hl[f * 32 + gn * 8];
        const float4 h1 = *(const float4*)&hl[f * 32 + gn * 8 + 4];
        const float hv[8] = {h0.x, h0.y, h0.z, h0.w, h1.x, h1.y, h1.z, h1.w};
        const float wv[4] = {w4.x, w4.y, w4.z, w4.w};
#pragma unroll
        for (int r = 0; r < 8; ++r)
#pragma unroll
            for (int c = 0; c < 4; ++c) acc[r][c] = fmaf(hv[r], wv[c], acc[r][c]);
    }
    const float4 bb = *(const float4*)&bd2[m0];
#pragma unroll
    for (int r = 0; r < 8; ++r) {
        float4 o;
        o.x = acc[r][0] + bb.x; o.y = acc[r][1] + bb.y;
        o.z = acc[r][2] + bb.z; o.w = acc[r][3] + bb.w;
        *(float4*)&out[OFF_IMU + (size_t)(n0 + gn * 8 + r) * 2400 + m0] = o;
    }
}

// ============================================================================
extern "C" void kernel_launch(void* const* d_in, const int* in_sizes, int n_in,
                              void* d_out, int out_size, void* d_ws, size_t ws_size,
                              hipStream_t stream)
{
    const float* x        = (const float*)d_in[0];
    const float* imu_mask = (const float*)d_in[1];
    const int*   imu_len  = (const int*)  d_in[2];
    const float* conv_w   = (const float*)d_in[3];
    const float* conv_b   = (const float*)d_in[4];
    const float* W_b1     = (const float*)d_in[5];
    const float* b_b1     = (const float*)d_in[6];
    const float* W_fc     = (const float*)d_in[7];
    const float* b_fc     = (const float*)d_in[8];
    const float* Wqkv     = (const float*)d_in[9];
    const float* Wo       = (const float*)d_in[10];
    const float* ln1_g    = (const float*)d_in[11];
    const float* ln1_b    = (const float*)d_in[12];
    const float* Wf1      = (const float*)d_in[13];
    const float* bf1      = (const float*)d_in[14];
    const float* Wf2      = (const float*)d_in[15];
    const float* bf2      = (const float*)d_in[16];
    const float* ln2_g    = (const float*)d_in[17];
    const float* ln2_b    = (const float*)d_in[18];
    const float* Wout     = (const float*)d_in[19];
    const float* bout     = (const float*)d_in[20];
    const float* Wd1      = (const float*)d_in[21];
    const float* bd1      = (const float*)d_in[22];
    const float* Wd2      = (const float*)d_in[23];
    const float* bd2      = (const float*)d_in[24];
    const float* Wa       = (const float*)d_in[25];
    const float* ba       = (const float*)d_in[26];

    float* out = (float*)d_out;
    float* wsf = (float*)d_ws;
    int*   wsi = (int*)d_ws;

    float* bridge = wsf + WS_BRIDGE;
    float* tr_ws  = wsf + WS_TR;
    int* segid  = wsi + WS_SEGID;
    int* ends   = wsi + WS_ENDS;
    int* starts = wsi + WS_STARTS;
    int* nk     = wsi + WS_NK;

    k1_conv_bridge<<<4096, 256, 0, stream>>>(x, conv_w, conv_b, W_b1, b_b1, bridge);
    k23_forcast_seg<<<32, 256, 0, stream>>>(bridge, imu_mask, W_fc, b_fc, imu_len,
                                            out, segid, ends, starts, nk);
    k4_attn<<<256, 256, 0, stream>>>(bridge, segid, imu_len, Wqkv, Wo, ln1_g, ln1_b,
                                     Wf1, bf1, Wf2, bf2, ln2_g, ln2_b, Wout, bout, tr_ws);
    k5_atoms<<<dim3(130, 32), 128, 0, stream>>>(x, tr_ws, ends, starts, nk, Wa, ba, out);
    k6_imu<<<dim3(256, 10), 256, 0, stream>>>(bridge, Wd1, bd1, Wd2, bd2, out);
}